// Round 9
// baseline (554.180 us; speedup 1.0000x reference)
//
#include <hip/hip_runtime.h>

typedef __bf16 bf16_t;
typedef __bf16 bf16x2 __attribute__((ext_vector_type(2)));
typedef __bf16 bf16x4 __attribute__((ext_vector_type(4)));
typedef __bf16 bf16x8 __attribute__((ext_vector_type(8)));
typedef _Float16 f16_t;
typedef _Float16 f16x4 __attribute__((ext_vector_type(4)));
typedef float floatx4 __attribute__((ext_vector_type(4)));
typedef float floatx16 __attribute__((ext_vector_type(16)));

#define S_H   (8 * 2048 * 256)   // elements per H buffer (4,194,304)

__device__ inline void split_hl(float v, bf16_t& hi, bf16_t& lo) {
    hi = (bf16_t)v;
    lo = (bf16_t)(v - (float)hi);
}

// ---------------- kernel 0: adj int32 -> bitmask (2048 rows x 64 words) ----------------
__global__ void adjbits_kernel(const int* __restrict__ adj, unsigned* __restrict__ bits) {
    int id = blockIdx.x * 256 + threadIdx.x;   // 131072 words
    const int* p = adj + (size_t)id * 32;
    unsigned w = 0;
#pragma unroll
    for (int j = 0; j < 32; j += 4) {
        int4 v = *(const int4*)(p + j);
        w |= (v.x > 0 ? 1u : 0u) << j;
        w |= (v.y > 0 ? 1u : 0u) << (j + 1);
        w |= (v.z > 0 ? 1u : 0u) << (j + 2);
        w |= (v.w > 0 ? 1u : 0u) << (j + 3);
    }
    bits[id] = w;
}

// ---------------- kernel 1: transpose + hi/lo split W (r6-verbatim) ----------------
__global__ void wtrans_kernel(const float* __restrict__ W1,
                              const float* __restrict__ W2,
                              const float* __restrict__ W3,
                              bf16_t* __restrict__ Wthi, bf16_t* __restrict__ Wtlo) {
    __shared__ float T[64 * 68];
    const int zi = blockIdx.z;
    const float* W = (zi == 0) ? W1 : ((zi == 1) ? W2 : W3);
    bf16_t* ohi = Wthi + zi * 256 * 256;
    bf16_t* olo = Wtlo + zi * 256 * 256;
    const int c0 = blockIdx.x * 64, d0 = blockIdx.y * 64;
    const int tid = threadIdx.x;
#pragma unroll
    for (int i = 0; i < 4; i++) {
        int idx = i * 256 + tid;
        int r = idx >> 4, c4 = (idx & 15) * 4;
        floatx4 v = *(const floatx4*)(W + (c0 + r) * 256 + d0 + c4);
        *(floatx4*)(&T[r * 68 + c4]) = v;
    }
    __syncthreads();
#pragma unroll
    for (int i = 0; i < 4; i++) {
        int idx = i * 256 + tid;
        int rd = idx & 63, cc4 = (idx >> 6) * 4;
        bf16x4 vh, vl;
#pragma unroll
        for (int ii = 0; ii < 4; ii++) {
            float v = T[(cc4 + ii) * 68 + rd];
            bf16_t h, l; split_hl(v, h, l);
            vh[ii] = h; vl[ii] = l;
        }
        *(bf16x4*)(ohi + (d0 + rd) * 256 + c0 + cc4) = vh;
        *(bf16x4*)(olo + (d0 + rd) * 256 + c0 + cc4) = vl;
    }
}

// ---------------- kernel 2: projections, bf16 hi/lo 3-chain (r6-verbatim) ----------------
__global__ __launch_bounds__(256) void proj_kernel(
    const float* __restrict__ X,
    const bf16_t* __restrict__ Wthi, const bf16_t* __restrict__ Wtlo,
    bf16_t* __restrict__ H1hi, bf16_t* __restrict__ H1lo,
    bf16_t* __restrict__ H2hi, bf16_t* __restrict__ H2lo,
    bf16_t* __restrict__ H3t) {
    __shared__ bf16_t Xh[64 * 40], Xl[64 * 40];
    __shared__ bf16_t Wh[256 * 40], Wl[256 * 40];
    const int z = blockIdx.y;
    const int row0 = blockIdx.x * 64;
    const int tid = threadIdx.x;
    const int w = tid >> 6, lane = tid & 63;
    const int m = lane & 15, q = lane >> 4;
    const bf16_t* Wzh = Wthi + z * 256 * 256;
    const bf16_t* Wzl = Wtlo + z * 256 * 256;

    floatx4 acc[16];
#pragma unroll
    for (int i = 0; i < 16; i++) acc[i] = (floatx4){0.f, 0.f, 0.f, 0.f};

    for (int c0 = 0; c0 < 256; c0 += 32) {
#pragma unroll
        for (int i = 0; i < 2; i++) {
            int idx = i * 256 + tid;
            int r = idx >> 3, c4 = (idx & 7) * 4;
            floatx4 v = *(const floatx4*)(X + (size_t)(row0 + r) * 256 + c0 + c4);
            bf16x4 vh, vl;
#pragma unroll
            for (int ii = 0; ii < 4; ii++) {
                bf16_t h, l; split_hl(v[ii], h, l);
                vh[ii] = h; vl[ii] = l;
            }
            *(bf16x4*)(&Xh[r * 40 + c4]) = vh;
            *(bf16x4*)(&Xl[r * 40 + c4]) = vl;
        }
#pragma unroll
        for (int i = 0; i < 4; i++) {
            int idx = i * 256 + tid;
            int d = idx >> 2, c8 = (idx & 3) * 8;
            *(bf16x8*)(&Wh[d * 40 + c8]) = *(const bf16x8*)(Wzh + d * 256 + c0 + c8);
            *(bf16x8*)(&Wl[d * 40 + c8]) = *(const bf16x8*)(Wzl + d * 256 + c0 + c8);
        }
        __syncthreads();
        bf16x8 ah = *(const bf16x8*)(&Xh[(w * 16 + m) * 40 + q * 8]);
        bf16x8 al = *(const bf16x8*)(&Xl[(w * 16 + m) * 40 + q * 8]);
#pragma unroll
        for (int nt = 0; nt < 16; nt++) {
            bf16x8 bh = *(const bf16x8*)(&Wh[(nt * 16 + m) * 40 + q * 8]);
            bf16x8 bl = *(const bf16x8*)(&Wl[(nt * 16 + m) * 40 + q * 8]);
            acc[nt] = __builtin_amdgcn_mfma_f32_16x16x32_bf16(ah, bh, acc[nt], 0, 0, 0);
            acc[nt] = __builtin_amdgcn_mfma_f32_16x16x32_bf16(ah, bl, acc[nt], 0, 0, 0);
            acc[nt] = __builtin_amdgcn_mfma_f32_16x16x32_bf16(al, bh, acc[nt], 0, 0, 0);
        }
        __syncthreads();
    }
    const int rbase = row0 + w * 16 + q * 4;
    if (z < 2) {
        bf16_t* Hhi = (z == 0) ? H1hi : H2hi;
        bf16_t* Hlo = (z == 0) ? H1lo : H2lo;
#pragma unroll
        for (int nt = 0; nt < 16; nt++)
#pragma unroll
            for (int r = 0; r < 4; r++) {
                bf16_t h, l; split_hl(acc[nt][r], h, l);
                int off = (rbase + r) * 256 + nt * 16 + m;
                Hhi[off] = h;
                Hlo[off] = l;
            }
    } else {
#pragma unroll
        for (int nt = 0; nt < 16; nt++)
#pragma unroll
            for (int r = 0; r < 4; r++) {
                int token = rbase + r;
                int b = token >> 11, n = token & 2047;
                H3t[(size_t)(b * 256 + nt * 16 + m) * 2048 + n] = (bf16_t)acc[nt][r];
            }
    }
}

// ---------------- kernel 3: flash attention, 32 q/wave, bf16 hi/lo scores ----------------
// r8-verified skeleton + r6-proven numerics. Wave owns 32 queries (Q hi/lo in regs
// as B-frags). Score = Khi·Qhi (chain sa) + [Khi·Qlo + Klo·Qhi] (chain sb). P,V bf16.
// LDS carved from ONE buffer; epilogue LT region [0,36864) provably in-bounds.
__global__ __launch_bounds__(512, 1) void attn_kernel(
    const bf16_t* __restrict__ H1hi, const bf16_t* __restrict__ H1lo,
    const bf16_t* __restrict__ H2hi, const bf16_t* __restrict__ H2lo,
    const bf16_t* __restrict__ H3t, const unsigned* __restrict__ adjbits,
    f16_t* __restrict__ Opart, float* __restrict__ mpart, float* __restrict__ lpart,
    int klen) {
    __shared__ __align__(16) char smem[74752];
    bf16_t* Khi = (bf16_t*)smem;               // [32 keys][264]  16,896 B @ 0
    bf16_t* Klo = (bf16_t*)(smem + 16896);     // [32 keys][264]  16,896 B
    bf16_t* Vf  = (bf16_t*)(smem + 33792);     // [256 d][40]     20,480 B
    bf16_t* Plb = (bf16_t*)(smem + 54272);     // 8 x [32 q][40]  20,480 B

    const int b = blockIdx.y;
    const int q0b = blockIdx.x * 256;
    const int kz = blockIdx.z;
    const int tid = threadIdx.x;
    const int w = tid >> 6, lane = tid & 63;
    const int lq = lane & 31;        // q-col / key-row / d-row index
    const int h = lane >> 5;         // k-half selector
    const int qg = q0b + w * 32 + lq;
    bf16_t* Pl = Plb + w * 1280;     // this wave's 32x40 P buffer

    // ---- Q fragments in registers: B[k][n=q], hi+lo, 16 chunks of k=16 ----
    bf16x8 qhi[16], qlo[16];
    {
        const bf16_t* qrh = H1hi + (size_t)(b * 2048 + qg) * 256;
        const bf16_t* qrl = H1lo + (size_t)(b * 2048 + qg) * 256;
#pragma unroll
        for (int ck = 0; ck < 16; ck++) {
            qhi[ck] = *(const bf16x8*)(qrh + ck * 16 + h * 8);
            qlo[ck] = *(const bf16x8*)(qrl + ck * 16 + h * 8);
        }
    }

    float m_run = -3.0e38f, l_run = 0.f;
    floatx16 o[8];
#pragma unroll
    for (int t = 0; t < 8; t++) o[t] = (floatx16)(0.f);

    bf16x8 rkh[2], rkl[2], rvv[2];
    const int kbeg = kz * klen, kend = kbeg + klen;

    // prefetch first K/V tile (K hi/lo: 1024 16B granules each; V: 1024; 512 thr -> 2 each)
#pragma unroll
    for (int i = 0; i < 2; i++) {
        int ci = i * 512 + tid;
        int krow = ci >> 5, kg = ci & 31;
        rkh[i] = *(const bf16x8*)(H2hi + (size_t)(b * 2048 + kbeg + krow) * 256 + kg * 8);
        rkl[i] = *(const bf16x8*)(H2lo + (size_t)(b * 2048 + kbeg + krow) * 256 + kg * 8);
        int vd = ci >> 2, vg = ci & 3;
        rvv[i] = *(const bf16x8*)(H3t + (size_t)(b * 256 + vd) * 2048 + kbeg + vg * 8);
    }

    for (int k0 = kbeg; k0 < kend; k0 += 32) {
        __syncthreads();   // prior iter's LDS readers done
#pragma unroll
        for (int i = 0; i < 2; i++) {
            int ci = i * 512 + tid;
            int krow = ci >> 5, kg = ci & 31;
            *(bf16x8*)(&Khi[krow * 264 + kg * 8]) = rkh[i];
            *(bf16x8*)(&Klo[krow * 264 + kg * 8]) = rkl[i];
            int vd = ci >> 2, vg = ci & 3;
            *(bf16x8*)(&Vf[vd * 40 + vg * 8]) = rvv[i];
        }
        __syncthreads();
        if (k0 + 32 < kend) {   // prefetch next tile while computing
            int kn = k0 + 32;
#pragma unroll
            for (int i = 0; i < 2; i++) {
                int ci = i * 512 + tid;
                int krow = ci >> 5, kg = ci & 31;
                rkh[i] = *(const bf16x8*)(H2hi + (size_t)(b * 2048 + kn + krow) * 256 + kg * 8);
                rkl[i] = *(const bf16x8*)(H2lo + (size_t)(b * 2048 + kn + krow) * 256 + kg * 8);
                int vd = ci >> 2, vg = ci & 3;
                rvv[i] = *(const bf16x8*)(H3t + (size_t)(b * 256 + vd) * 2048 + kn + vg * 8);
            }
        }

        // ---- S^T = K·Q^T : sa = hi·hi, sb = hi·lo + lo·hi (full cross terms) ----
        floatx16 sa = (floatx16)(0.f), sb = (floatx16)(0.f);
#pragma unroll
        for (int ck = 0; ck < 16; ck++) {
            bf16x8 kh = *(const bf16x8*)(&Khi[lq * 264 + ck * 16 + h * 8]);
            bf16x8 kl = *(const bf16x8*)(&Klo[lq * 264 + ck * 16 + h * 8]);
            sa = __builtin_amdgcn_mfma_f32_32x32x16_bf16(kh, qhi[ck], sa, 0, 0, 0);
            sb = __builtin_amdgcn_mfma_f32_32x32x16_bf16(kh, qlo[ck], sb, 0, 0, 0);
            sb = __builtin_amdgcn_mfma_f32_32x32x16_bf16(kl, qhi[ck], sb, 0, 0, 0);
        }

        // ---- leaky-relu + mask + per-q (per-lane) tile max, in place in sa ----
        unsigned aw = adjbits[(size_t)qg * 64 + (k0 >> 5)];
        unsigned awh = h ? (aw >> 4) : aw;   // fold key's +4h bit into the shift
        float tmax = -3.0e38f;
#pragma unroll
        for (int r = 0; r < 16; r++) {
            float v = sa[r] + sb[r];
            v = (v > 0.f) ? v : 0.2f * v;
            int keyl = (r & 3) + 8 * (r >> 2);   // + 4h via awh
            v = ((awh >> keyl) & 1u) ? v : -1.0e12f;
            sa[r] = v;
            tmax = fmaxf(tmax, v);
        }
        tmax = fmaxf(tmax, __shfl_xor(tmax, 32, 64));

        // ---- online softmax (skip rescale when max didn't rise) ----
        float mnew = fmaxf(m_run, tmax);
        if (__any(mnew > m_run)) {
            float alpha = __expf(m_run - mnew);
            m_run = mnew;
            l_run *= alpha;
#pragma unroll
            for (int t = 0; t < 8; t++)
#pragma unroll
                for (int r = 0; r < 16; r++) o[t][r] *= alpha;
        }
        float rs = 0.f;
#pragma unroll
        for (int r = 0; r < 16; r++) {
            float e = __expf(sa[r] - m_run);
            sa[r] = e;
            rs += e;
        }
        rs += __shfl_xor(rs, 32, 64);
        l_run += rs;

        // ---- P: C-layout -> per-wave LDS [q][key] -> B-layout frags ----
#pragma unroll
        for (int mreg = 0; mreg < 8; mreg++) {
            int keyl = 2 * (mreg & 1) + 8 * (mreg >> 1) + 4 * h;
            bf16x2 pk;
            pk[0] = (bf16_t)sa[2 * mreg];
            pk[1] = (bf16_t)sa[2 * mreg + 1];
            *(bf16x2*)(&Pl[lq * 40 + keyl]) = pk;
        }
        bf16x8 pf0 = *(const bf16x8*)(&Pl[lq * 40 + h * 8]);
        bf16x8 pf1 = *(const bf16x8*)(&Pl[lq * 40 + 16 + h * 8]);

        // ---- O^T += V^T·P : A = V-frag (m=d), B = P-frag (n=q) ----
#pragma unroll
        for (int t = 0; t < 8; t++) {
            bf16x8 v0 = *(const bf16x8*)(&Vf[(t * 32 + lq) * 40 + h * 8]);
            bf16x8 v1 = *(const bf16x8*)(&Vf[(t * 32 + lq) * 40 + 16 + h * 8]);
            o[t] = __builtin_amdgcn_mfma_f32_32x32x16_bf16(v0, pf0, o[t], 0, 0, 0);
            o[t] = __builtin_amdgcn_mfma_f32_32x32x16_bf16(v1, pf1, o[t], 0, 0, 0);
        }
    }

    // ---- epilogue: per-wave LDS transpose O^T -> row-major fp16 partials ----
    const int rowg = kz * 16384 + b * 2048 + q0b + w * 32;
    float* LT = ((float*)smem) + w * 1152;   // 8 waves x 4608 B = 36,864 <= 74,752
#pragma unroll 1
    for (int t = 0; t < 8; t++) {
        __syncthreads();
#pragma unroll
        for (int r = 0; r < 16; r++) {
            int dsub = (r & 3) + 8 * (r >> 2) + 4 * h;
            LT[lq * 36 + dsub] = o[t][r];
        }
        __syncthreads();
#pragma unroll
        for (int pp = 0; pp < 4; pp++) {
            int qq = pp * 8 + (lane >> 3), dc = (lane & 7) * 4;
            floatx4 v = *(const floatx4*)(&LT[qq * 36 + dc]);
            f16x4 vh;
#pragma unroll
            for (int ii = 0; ii < 4; ii++) vh[ii] = (f16_t)v[ii];
            *(f16x4*)(&Opart[(size_t)(rowg + qq) * 256 + t * 32 + dc]) = vh;
        }
    }
    if (h == 0) {
        mpart[rowg + lq] = m_run;
        lpart[rowg + lq] = l_run;
    }
}

// ---------------- kernel 4: merge splits + normalize + relu ----------------
__global__ __launch_bounds__(256) void merge_kernel(
    const f16_t* __restrict__ Opart, const float* __restrict__ mpart,
    const float* __restrict__ lpart, float* __restrict__ out, int S) {
    int gid = blockIdx.x * 256 + threadIdx.x;   // 16384 rows x 64 col-chunks
    int row = gid >> 6, c4 = (gid & 63) * 4;
    float M = -3.0e38f;
    for (int s = 0; s < S; s++) M = fmaxf(M, mpart[s * 16384 + row]);
    float denom = 0.f;
    float4 acc = make_float4(0.f, 0.f, 0.f, 0.f);
    for (int s = 0; s < S; s++) {
        float sc = __expf(mpart[s * 16384 + row] - M);
        denom += lpart[s * 16384 + row] * sc;
        f16x4 v = *(const f16x4*)(Opart + ((size_t)(s * 16384 + row)) * 256 + c4);
        acc.x += (float)v[0] * sc; acc.y += (float)v[1] * sc;
        acc.z += (float)v[2] * sc; acc.w += (float)v[3] * sc;
    }
    float inv = 1.f / denom;
    float4 r;
    r.x = fmaxf(acc.x * inv, 0.f);
    r.y = fmaxf(acc.y * inv, 0.f);
    r.z = fmaxf(acc.z * inv, 0.f);
    r.w = fmaxf(acc.w * inv, 0.f);
    *(float4*)(out + (size_t)row * 256 + c4) = r;
}

extern "C" void kernel_launch(void* const* d_in, const int* in_sizes, int n_in,
                              void* d_out, int out_size, void* d_ws, size_t ws_size,
                              hipStream_t stream) {
    const float* X   = (const float*)d_in[0];
    const int*   adj = (const int*)d_in[1];
    const float* W1  = (const float*)d_in[2];
    const float* W2  = (const float*)d_in[3];
    const float* W3  = (const float*)d_in[4];
    float* out = (float*)d_out;

    char* ws = (char*)d_ws;
    bf16_t* H1hi = (bf16_t*)(ws + (size_t)0 * S_H * 2);
    bf16_t* H1lo = (bf16_t*)(ws + (size_t)1 * S_H * 2);
    bf16_t* H2hi = (bf16_t*)(ws + (size_t)2 * S_H * 2);
    bf16_t* H2lo = (bf16_t*)(ws + (size_t)3 * S_H * 2);
    bf16_t* H3t  = (bf16_t*)(ws + (size_t)4 * S_H * 2);
    size_t off = (size_t)5 * S_H * 2;                    // 41,943,040
    bf16_t* Wthi = (bf16_t*)(ws + off);                  // 393,216 B
    bf16_t* Wtlo = (bf16_t*)(ws + off + 393216);         // 393,216 B
    float* mpart = (float*)(ws + off);                   // overlays Wt (dead after proj)
    float* lpart = (float*)(ws + off + 262144);          // 4*16384*4 each, fits in 786,432
    unsigned* adjb = (unsigned*)(ws + off + 786432);     // 524,288 B
    size_t opart_off = off + 786432 + 524288;            // 43,253,760
    f16_t* Opart = (f16_t*)(ws + opart_off);

    const size_t need4 = opart_off + (size_t)4 * 16384 * 256 * 2;  // 76,808,192 (proven)
    const size_t need2 = opart_off + (size_t)2 * 16384 * 256 * 2;
    int S = (ws_size >= need4) ? 4 : ((ws_size >= need2) ? 2 : 1);

    adjbits_kernel<<<512, 256, 0, stream>>>(adj, adjb);
    wtrans_kernel<<<dim3(4, 4, 3), 256, 0, stream>>>(W1, W2, W3, Wthi, Wtlo);
    proj_kernel<<<dim3(256, 3), 256, 0, stream>>>(X, Wthi, Wtlo,
                                                  H1hi, H1lo, H2hi, H2lo, H3t);
    attn_kernel<<<dim3(8, 8, S), 512, 0, stream>>>(H1hi, H1lo, H2hi, H2lo, H3t,
                                                   adjb, Opart, mpart, lpart, 2048 / S);
    merge_kernel<<<4096, 256, 0, stream>>>(Opart, mpart, lpart, out, S);
}

// Round 10
// 385.367 us; speedup vs baseline: 1.4381x; 1.4381x over previous
//
#include <hip/hip_runtime.h>

typedef __bf16 bf16_t;
typedef __bf16 bf16x4 __attribute__((ext_vector_type(4)));
typedef __bf16 bf16x8 __attribute__((ext_vector_type(8)));
typedef _Float16 f16_t;
typedef _Float16 f16x2 __attribute__((ext_vector_type(2)));
typedef _Float16 f16x4 __attribute__((ext_vector_type(4)));
typedef _Float16 f16x8 __attribute__((ext_vector_type(8)));
typedef float floatx4 __attribute__((ext_vector_type(4)));
typedef float floatx16 __attribute__((ext_vector_type(16)));

#define S_H   (8 * 2048 * 256)   // elements per H buffer (4,194,304)

__device__ inline void split_hl(float v, bf16_t& hi, bf16_t& lo) {
    hi = (bf16_t)v;
    lo = (bf16_t)(v - (float)hi);
}
__device__ inline void split_hl_f16(float v, f16_t& hi, f16_t& lo) {
    hi = (f16_t)v;
    lo = (f16_t)(v - (float)hi);
}

// ---------------- kernel 0: adj int32 -> bitmask (2048 rows x 64 words) ----------------
__global__ void adjbits_kernel(const int* __restrict__ adj, unsigned* __restrict__ bits) {
    int id = blockIdx.x * 256 + threadIdx.x;   // 131072 words
    const int* p = adj + (size_t)id * 32;
    unsigned w = 0;
#pragma unroll
    for (int j = 0; j < 32; j += 4) {
        int4 v = *(const int4*)(p + j);
        w |= (v.x > 0 ? 1u : 0u) << j;
        w |= (v.y > 0 ? 1u : 0u) << (j + 1);
        w |= (v.z > 0 ? 1u : 0u) << (j + 2);
        w |= (v.w > 0 ? 1u : 0u) << (j + 3);
    }
    bits[id] = w;
}

// ---------------- kernel 1: transpose + hi/lo split W (r6-verbatim, bf16) ----------------
__global__ void wtrans_kernel(const float* __restrict__ W1,
                              const float* __restrict__ W2,
                              const float* __restrict__ W3,
                              bf16_t* __restrict__ Wthi, bf16_t* __restrict__ Wtlo) {
    __shared__ float T[64 * 68];
    const int zi = blockIdx.z;
    const float* W = (zi == 0) ? W1 : ((zi == 1) ? W2 : W3);
    bf16_t* ohi = Wthi + zi * 256 * 256;
    bf16_t* olo = Wtlo + zi * 256 * 256;
    const int c0 = blockIdx.x * 64, d0 = blockIdx.y * 64;
    const int tid = threadIdx.x;
#pragma unroll
    for (int i = 0; i < 4; i++) {
        int idx = i * 256 + tid;
        int r = idx >> 4, c4 = (idx & 15) * 4;
        floatx4 v = *(const floatx4*)(W + (c0 + r) * 256 + d0 + c4);
        *(floatx4*)(&T[r * 68 + c4]) = v;
    }
    __syncthreads();
#pragma unroll
    for (int i = 0; i < 4; i++) {
        int idx = i * 256 + tid;
        int rd = idx & 63, cc4 = (idx >> 6) * 4;
        bf16x4 vh, vl;
#pragma unroll
        for (int ii = 0; ii < 4; ii++) {
            float v = T[(cc4 + ii) * 68 + rd];
            bf16_t h, l; split_hl(v, h, l);
            vh[ii] = h; vl[ii] = l;
        }
        *(bf16x4*)(ohi + (d0 + rd) * 256 + c0 + cc4) = vh;
        *(bf16x4*)(olo + (d0 + rd) * 256 + c0 + cc4) = vl;
    }
}

// ---------------- kernel 2: projections, bf16 hi/lo 3-chain compute (r6-proven) ----------------
// Output dtypes changed: z=0 -> H1f fp16 single; z=1 -> H2 fp16 hi+lo; z=2 -> H3t fp16.
__global__ __launch_bounds__(256) void proj_kernel(
    const float* __restrict__ X,
    const bf16_t* __restrict__ Wthi, const bf16_t* __restrict__ Wtlo,
    f16_t* __restrict__ H1f,
    f16_t* __restrict__ H2hi, f16_t* __restrict__ H2lo,
    f16_t* __restrict__ H3t) {
    __shared__ bf16_t Xh[64 * 40], Xl[64 * 40];
    __shared__ bf16_t Wh[256 * 40], Wl[256 * 40];
    const int z = blockIdx.y;
    const int row0 = blockIdx.x * 64;
    const int tid = threadIdx.x;
    const int w = tid >> 6, lane = tid & 63;
    const int m = lane & 15, q = lane >> 4;
    const bf16_t* Wzh = Wthi + z * 256 * 256;
    const bf16_t* Wzl = Wtlo + z * 256 * 256;

    floatx4 acc[16];
#pragma unroll
    for (int i = 0; i < 16; i++) acc[i] = (floatx4){0.f, 0.f, 0.f, 0.f};

    for (int c0 = 0; c0 < 256; c0 += 32) {
#pragma unroll
        for (int i = 0; i < 2; i++) {
            int idx = i * 256 + tid;
            int r = idx >> 3, c4 = (idx & 7) * 4;
            floatx4 v = *(const floatx4*)(X + (size_t)(row0 + r) * 256 + c0 + c4);
            bf16x4 vh, vl;
#pragma unroll
            for (int ii = 0; ii < 4; ii++) {
                bf16_t h, l; split_hl(v[ii], h, l);
                vh[ii] = h; vl[ii] = l;
            }
            *(bf16x4*)(&Xh[r * 40 + c4]) = vh;
            *(bf16x4*)(&Xl[r * 40 + c4]) = vl;
        }
#pragma unroll
        for (int i = 0; i < 4; i++) {
            int idx = i * 256 + tid;
            int d = idx >> 2, c8 = (idx & 3) * 8;
            *(bf16x8*)(&Wh[d * 40 + c8]) = *(const bf16x8*)(Wzh + d * 256 + c0 + c8);
            *(bf16x8*)(&Wl[d * 40 + c8]) = *(const bf16x8*)(Wzl + d * 256 + c0 + c8);
        }
        __syncthreads();
        bf16x8 ah = *(const bf16x8*)(&Xh[(w * 16 + m) * 40 + q * 8]);
        bf16x8 al = *(const bf16x8*)(&Xl[(w * 16 + m) * 40 + q * 8]);
#pragma unroll
        for (int nt = 0; nt < 16; nt++) {
            bf16x8 bh = *(const bf16x8*)(&Wh[(nt * 16 + m) * 40 + q * 8]);
            bf16x8 bl = *(const bf16x8*)(&Wl[(nt * 16 + m) * 40 + q * 8]);
            acc[nt] = __builtin_amdgcn_mfma_f32_16x16x32_bf16(ah, bh, acc[nt], 0, 0, 0);
            acc[nt] = __builtin_amdgcn_mfma_f32_16x16x32_bf16(ah, bl, acc[nt], 0, 0, 0);
            acc[nt] = __builtin_amdgcn_mfma_f32_16x16x32_bf16(al, bh, acc[nt], 0, 0, 0);
        }
        __syncthreads();
    }
    const int rbase = row0 + w * 16 + q * 4;
    if (z == 0) {
#pragma unroll
        for (int nt = 0; nt < 16; nt++)
#pragma unroll
            for (int r = 0; r < 4; r++)
                H1f[(size_t)(rbase + r) * 256 + nt * 16 + m] = (f16_t)acc[nt][r];
    } else if (z == 1) {
#pragma unroll
        for (int nt = 0; nt < 16; nt++)
#pragma unroll
            for (int r = 0; r < 4; r++) {
                f16_t h, l; split_hl_f16(acc[nt][r], h, l);
                int off = (rbase + r) * 256 + nt * 16 + m;
                H2hi[off] = h;
                H2lo[off] = l;
            }
    } else {
#pragma unroll
        for (int nt = 0; nt < 16; nt++)
#pragma unroll
            for (int r = 0; r < 4; r++) {
                int token = rbase + r;
                int b = token >> 11, n = token & 2047;
                H3t[(size_t)(b * 256 + nt * 16 + m) * 2048 + n] = (f16_t)acc[nt][r];
            }
    }
}

// ---------------- kernel 3: flash attention, 32 q/wave, fp16 Q single + fp16 K hi/lo ----------------
// r9-verified skeleton. Q single fp16 (64 regs) + o (128 AGPR) + sa (16 AGPR) fits
// the 256-unified budget of a 512-thread block -> no spill (the r9 failure mode).
// Score = (Khi + Klo)·Q accumulated in ONE chain. P,V fp16.
__global__ __launch_bounds__(512, 1) void attn_kernel(
    const f16_t* __restrict__ H1f,
    const f16_t* __restrict__ H2hi, const f16_t* __restrict__ H2lo,
    const f16_t* __restrict__ H3t, const unsigned* __restrict__ adjbits,
    f16_t* __restrict__ Opart, float* __restrict__ mpart, float* __restrict__ lpart,
    int klen) {
    __shared__ __align__(16) char smem[74752];
    f16_t* Khi = (f16_t*)smem;                 // [32 keys][264]  16,896 B @ 0
    f16_t* Klo = (f16_t*)(smem + 16896);       // [32 keys][264]  16,896 B
    f16_t* Vf  = (f16_t*)(smem + 33792);       // [256 d][40]     20,480 B
    f16_t* Plb = (f16_t*)(smem + 54272);       // 8 x [32 q][40]  20,480 B

    const int b = blockIdx.y;
    const int q0b = blockIdx.x * 256;
    const int kz = blockIdx.z;
    const int tid = threadIdx.x;
    const int w = tid >> 6, lane = tid & 63;
    const int lq = lane & 31;        // q-col / key-row / d-row index
    const int h = lane >> 5;         // k-half selector
    const int qg = q0b + w * 32 + lq;
    f16_t* Pl = Plb + w * 1280;      // this wave's 32x40 P buffer

    // ---- Q fragments in registers: B[k][n=q], single fp16, 16 chunks of k=16 ----
    f16x8 qf[16];
    {
        const f16_t* qr = H1f + (size_t)(b * 2048 + qg) * 256;
#pragma unroll
        for (int ck = 0; ck < 16; ck++)
            qf[ck] = *(const f16x8*)(qr + ck * 16 + h * 8);
    }

    float m_run = -3.0e38f, l_run = 0.f;
    floatx16 o[8];
#pragma unroll
    for (int t = 0; t < 8; t++) o[t] = (floatx16)(0.f);

    f16x8 rkh[2], rkl[2], rvv[2];
    const int kbeg = kz * klen, kend = kbeg + klen;

    // prefetch first K/V tile (1024 16B granules each; 512 thr -> 2 each)
#pragma unroll
    for (int i = 0; i < 2; i++) {
        int ci = i * 512 + tid;
        int krow = ci >> 5, kg = ci & 31;
        rkh[i] = *(const f16x8*)(H2hi + (size_t)(b * 2048 + kbeg + krow) * 256 + kg * 8);
        rkl[i] = *(const f16x8*)(H2lo + (size_t)(b * 2048 + kbeg + krow) * 256 + kg * 8);
        int vd = ci >> 2, vg = ci & 3;
        rvv[i] = *(const f16x8*)(H3t + (size_t)(b * 256 + vd) * 2048 + kbeg + vg * 8);
    }

    for (int k0 = kbeg; k0 < kend; k0 += 32) {
        __syncthreads();   // prior iter's LDS readers done
#pragma unroll
        for (int i = 0; i < 2; i++) {
            int ci = i * 512 + tid;
            int krow = ci >> 5, kg = ci & 31;
            *(f16x8*)(&Khi[krow * 264 + kg * 8]) = rkh[i];
            *(f16x8*)(&Klo[krow * 264 + kg * 8]) = rkl[i];
            int vd = ci >> 2, vg = ci & 3;
            *(f16x8*)(&Vf[vd * 40 + vg * 8]) = rvv[i];
        }
        __syncthreads();
        if (k0 + 32 < kend) {   // prefetch next tile while computing
            int kn = k0 + 32;
#pragma unroll
            for (int i = 0; i < 2; i++) {
                int ci = i * 512 + tid;
                int krow = ci >> 5, kg = ci & 31;
                rkh[i] = *(const f16x8*)(H2hi + (size_t)(b * 2048 + kn + krow) * 256 + kg * 8);
                rkl[i] = *(const f16x8*)(H2lo + (size_t)(b * 2048 + kn + krow) * 256 + kg * 8);
                int vd = ci >> 2, vg = ci & 3;
                rvv[i] = *(const f16x8*)(H3t + (size_t)(b * 256 + vd) * 2048 + kn + vg * 8);
            }
        }

        // ---- S^T = K·Q^T : sa = Khi·Q + Klo·Q (one chain) ----
        floatx16 sa = (floatx16)(0.f);
#pragma unroll
        for (int ck = 0; ck < 16; ck++) {
            f16x8 kh = *(const f16x8*)(&Khi[lq * 264 + ck * 16 + h * 8]);
            f16x8 kl = *(const f16x8*)(&Klo[lq * 264 + ck * 16 + h * 8]);
            sa = __builtin_amdgcn_mfma_f32_32x32x16_f16(kh, qf[ck], sa, 0, 0, 0);
            sa = __builtin_amdgcn_mfma_f32_32x32x16_f16(kl, qf[ck], sa, 0, 0, 0);
        }

        // ---- leaky-relu + mask + per-q (per-lane) tile max, in place ----
        unsigned aw = adjbits[(size_t)qg * 64 + (k0 >> 5)];
        unsigned awh = h ? (aw >> 4) : aw;   // fold key's +4h bit into the shift
        float tmax = -3.0e38f;
#pragma unroll
        for (int r = 0; r < 16; r++) {
            float v = sa[r];
            v = (v > 0.f) ? v : 0.2f * v;
            int keyl = (r & 3) + 8 * (r >> 2);   // + 4h via awh
            v = ((awh >> keyl) & 1u) ? v : -1.0e12f;
            sa[r] = v;
            tmax = fmaxf(tmax, v);
        }
        tmax = fmaxf(tmax, __shfl_xor(tmax, 32, 64));

        // ---- online softmax (skip rescale when max didn't rise) ----
        float mnew = fmaxf(m_run, tmax);
        if (__any(mnew > m_run)) {
            float alpha = __expf(m_run - mnew);
            m_run = mnew;
            l_run *= alpha;
#pragma unroll
            for (int t = 0; t < 8; t++)
#pragma unroll
                for (int r = 0; r < 16; r++) o[t][r] *= alpha;
        }
        float rs = 0.f;
#pragma unroll
        for (int r = 0; r < 16; r++) {
            float e = __expf(sa[r] - m_run);
            sa[r] = e;
            rs += e;
        }
        rs += __shfl_xor(rs, 32, 64);
        l_run += rs;

        // ---- P: C-layout -> per-wave LDS [q][key] -> B-layout frags ----
#pragma unroll
        for (int mreg = 0; mreg < 8; mreg++) {
            int keyl = 2 * (mreg & 1) + 8 * (mreg >> 1) + 4 * h;
            f16x2 pk;
            pk[0] = (f16_t)sa[2 * mreg];
            pk[1] = (f16_t)sa[2 * mreg + 1];
            *(f16x2*)(&Pl[lq * 40 + keyl]) = pk;
        }
        f16x8 pf0 = *(const f16x8*)(&Pl[lq * 40 + h * 8]);
        f16x8 pf1 = *(const f16x8*)(&Pl[lq * 40 + 16 + h * 8]);

        // ---- O^T += V^T·P : A = V-frag (m=d), B = P-frag (n=q) ----
#pragma unroll
        for (int t = 0; t < 8; t++) {
            f16x8 v0 = *(const f16x8*)(&Vf[(t * 32 + lq) * 40 + h * 8]);
            f16x8 v1 = *(const f16x8*)(&Vf[(t * 32 + lq) * 40 + 16 + h * 8]);
            o[t] = __builtin_amdgcn_mfma_f32_32x32x16_f16(v0, pf0, o[t], 0, 0, 0);
            o[t] = __builtin_amdgcn_mfma_f32_32x32x16_f16(v1, pf1, o[t], 0, 0, 0);
        }
    }

    // ---- epilogue: per-wave LDS transpose O^T -> row-major fp16 partials ----
    const int rowg = kz * 16384 + b * 2048 + q0b + w * 32;
    float* LT = ((float*)smem) + w * 1152;   // 8 waves x 4608 B = 36,864 <= 74,752
#pragma unroll 1
    for (int t = 0; t < 8; t++) {
        __syncthreads();
#pragma unroll
        for (int r = 0; r < 16; r++) {
            int dsub = (r & 3) + 8 * (r >> 2) + 4 * h;
            LT[lq * 36 + dsub] = o[t][r];
        }
        __syncthreads();
#pragma unroll
        for (int pp = 0; pp < 4; pp++) {
            int qq = pp * 8 + (lane >> 3), dc = (lane & 7) * 4;
            floatx4 v = *(const floatx4*)(&LT[qq * 36 + dc]);
            f16x4 vh;
#pragma unroll
            for (int ii = 0; ii < 4; ii++) vh[ii] = (f16_t)v[ii];
            *(f16x4*)(&Opart[(size_t)(rowg + qq) * 256 + t * 32 + dc]) = vh;
        }
    }
    if (h == 0) {
        mpart[rowg + lq] = m_run;
        lpart[rowg + lq] = l_run;
    }
}

// ---------------- kernel 4: merge splits + normalize + relu ----------------
__global__ __launch_bounds__(256) void merge_kernel(
    const f16_t* __restrict__ Opart, const float* __restrict__ mpart,
    const float* __restrict__ lpart, float* __restrict__ out, int S) {
    int gid = blockIdx.x * 256 + threadIdx.x;   // 16384 rows x 64 col-chunks
    int row = gid >> 6, c4 = (gid & 63) * 4;
    float M = -3.0e38f;
    for (int s = 0; s < S; s++) M = fmaxf(M, mpart[s * 16384 + row]);
    float denom = 0.f;
    float4 acc = make_float4(0.f, 0.f, 0.f, 0.f);
    for (int s = 0; s < S; s++) {
        float sc = __expf(mpart[s * 16384 + row] - M);
        denom += lpart[s * 16384 + row] * sc;
        f16x4 v = *(const f16x4*)(Opart + ((size_t)(s * 16384 + row)) * 256 + c4);
        acc.x += (float)v[0] * sc; acc.y += (float)v[1] * sc;
        acc.z += (float)v[2] * sc; acc.w += (float)v[3] * sc;
    }
    float inv = 1.f / denom;
    float4 r;
    r.x = fmaxf(acc.x * inv, 0.f);
    r.y = fmaxf(acc.y * inv, 0.f);
    r.z = fmaxf(acc.z * inv, 0.f);
    r.w = fmaxf(acc.w * inv, 0.f);
    *(float4*)(out + (size_t)row * 256 + c4) = r;
}

extern "C" void kernel_launch(void* const* d_in, const int* in_sizes, int n_in,
                              void* d_out, int out_size, void* d_ws, size_t ws_size,
                              hipStream_t stream) {
    const float* X   = (const float*)d_in[0];
    const int*   adj = (const int*)d_in[1];
    const float* W1  = (const float*)d_in[2];
    const float* W2  = (const float*)d_in[3];
    const float* W3  = (const float*)d_in[4];
    float* out = (float*)d_out;

    char* ws = (char*)d_ws;
    f16_t* H1f  = (f16_t*)(ws + (size_t)0 * S_H * 2);
    f16_t* H2hi = (f16_t*)(ws + (size_t)1 * S_H * 2);
    f16_t* H2lo = (f16_t*)(ws + (size_t)2 * S_H * 2);
    f16_t* H3t  = (f16_t*)(ws + (size_t)3 * S_H * 2);
    size_t off = (size_t)4 * S_H * 2;                    // 33,554,432
    bf16_t* Wthi = (bf16_t*)(ws + off);                  // 393,216 B
    bf16_t* Wtlo = (bf16_t*)(ws + off + 393216);         // 393,216 B
    float* mpart = (float*)(ws + off);                   // overlays Wt (dead after proj)
    float* lpart = (float*)(ws + off + 262144);          // 4*16384*4 each, fits 786,432
    unsigned* adjb = (unsigned*)(ws + off + 786432);     // 524,288 B
    size_t opart_off = off + 786432 + 524288;            // 34,865,152
    f16_t* Opart = (f16_t*)(ws + opart_off);

    const size_t need4 = opart_off + (size_t)4 * 16384 * 256 * 2;  // 68,419,584
    const size_t need2 = opart_off + (size_t)2 * 16384 * 256 * 2;
    int S = (ws_size >= need4) ? 4 : ((ws_size >= need2) ? 2 : 1);

    adjbits_kernel<<<512, 256, 0, stream>>>(adj, adjb);
    wtrans_kernel<<<dim3(4, 4, 3), 256, 0, stream>>>(W1, W2, W3, Wthi, Wtlo);
    proj_kernel<<<dim3(256, 3), 256, 0, stream>>>(X, Wthi, Wtlo,
                                                  H1f, H2hi, H2lo, H3t);
    attn_kernel<<<dim3(8, 8, S), 512, 0, stream>>>(H1f, H2hi, H2lo, H3t,
                                                   adjb, Opart, mpart, lpart, 2048 / S);
    merge_kernel<<<4096, 256, 0, stream>>>(Opart, mpart, lpart, out, S);
}

// Round 11
// 340.728 us; speedup vs baseline: 1.6265x; 1.1310x over previous
//
#include <hip/hip_runtime.h>

typedef __bf16 bf16_t;
typedef __bf16 bf16x4 __attribute__((ext_vector_type(4)));
typedef __bf16 bf16x8 __attribute__((ext_vector_type(8)));
typedef _Float16 f16_t;
typedef _Float16 f16x2 __attribute__((ext_vector_type(2)));
typedef _Float16 f16x4 __attribute__((ext_vector_type(4)));
typedef _Float16 f16x8 __attribute__((ext_vector_type(8)));
typedef float floatx4 __attribute__((ext_vector_type(4)));
typedef float floatx16 __attribute__((ext_vector_type(16)));

#define S_H   (8 * 2048 * 256)   // elements per H buffer (4,194,304)

__device__ inline void split_hl(float v, bf16_t& hi, bf16_t& lo) {
    hi = (bf16_t)v;
    lo = (bf16_t)(v - (float)hi);
}

// ---------------- kernel 0: adj int32 -> bitmask (2048 rows x 64 words) ----------------
__global__ void adjbits_kernel(const int* __restrict__ adj, unsigned* __restrict__ bits) {
    int id = blockIdx.x * 256 + threadIdx.x;   // 131072 words
    const int* p = adj + (size_t)id * 32;
    unsigned w = 0;
#pragma unroll
    for (int j = 0; j < 32; j += 4) {
        int4 v = *(const int4*)(p + j);
        w |= (v.x > 0 ? 1u : 0u) << j;
        w |= (v.y > 0 ? 1u : 0u) << (j + 1);
        w |= (v.z > 0 ? 1u : 0u) << (j + 2);
        w |= (v.w > 0 ? 1u : 0u) << (j + 3);
    }
    bits[id] = w;
}

// ---------------- kernel 1: transpose + hi/lo split W (r6-verbatim, bf16) ----------------
__global__ void wtrans_kernel(const float* __restrict__ W1,
                              const float* __restrict__ W2,
                              const float* __restrict__ W3,
                              bf16_t* __restrict__ Wthi, bf16_t* __restrict__ Wtlo) {
    __shared__ float T[64 * 68];
    const int zi = blockIdx.z;
    const float* W = (zi == 0) ? W1 : ((zi == 1) ? W2 : W3);
    bf16_t* ohi = Wthi + zi * 256 * 256;
    bf16_t* olo = Wtlo + zi * 256 * 256;
    const int c0 = blockIdx.x * 64, d0 = blockIdx.y * 64;
    const int tid = threadIdx.x;
#pragma unroll
    for (int i = 0; i < 4; i++) {
        int idx = i * 256 + tid;
        int r = idx >> 4, c4 = (idx & 15) * 4;
        floatx4 v = *(const floatx4*)(W + (c0 + r) * 256 + d0 + c4);
        *(floatx4*)(&T[r * 68 + c4]) = v;
    }
    __syncthreads();
#pragma unroll
    for (int i = 0; i < 4; i++) {
        int idx = i * 256 + tid;
        int rd = idx & 63, cc4 = (idx >> 6) * 4;
        bf16x4 vh, vl;
#pragma unroll
        for (int ii = 0; ii < 4; ii++) {
            float v = T[(cc4 + ii) * 68 + rd];
            bf16_t h, l; split_hl(v, h, l);
            vh[ii] = h; vl[ii] = l;
        }
        *(bf16x4*)(ohi + (d0 + rd) * 256 + c0 + cc4) = vh;
        *(bf16x4*)(olo + (d0 + rd) * 256 + c0 + cc4) = vl;
    }
}

// ---------------- kernel 2: projections, bf16 hi/lo 3-chain compute (r6-proven) ----------------
// Outputs: z=0 -> H1f fp16; z=1 -> H2f fp16; z=2 -> H3t fp16 (transposed).
__global__ __launch_bounds__(256) void proj_kernel(
    const float* __restrict__ X,
    const bf16_t* __restrict__ Wthi, const bf16_t* __restrict__ Wtlo,
    f16_t* __restrict__ H1f, f16_t* __restrict__ H2f, f16_t* __restrict__ H3t) {
    __shared__ bf16_t Xh[64 * 40], Xl[64 * 40];
    __shared__ bf16_t Wh[256 * 40], Wl[256 * 40];
    const int z = blockIdx.y;
    const int row0 = blockIdx.x * 64;
    const int tid = threadIdx.x;
    const int w = tid >> 6, lane = tid & 63;
    const int m = lane & 15, q = lane >> 4;
    const bf16_t* Wzh = Wthi + z * 256 * 256;
    const bf16_t* Wzl = Wtlo + z * 256 * 256;

    floatx4 acc[16];
#pragma unroll
    for (int i = 0; i < 16; i++) acc[i] = (floatx4){0.f, 0.f, 0.f, 0.f};

    for (int c0 = 0; c0 < 256; c0 += 32) {
#pragma unroll
        for (int i = 0; i < 2; i++) {
            int idx = i * 256 + tid;
            int r = idx >> 3, c4 = (idx & 7) * 4;
            floatx4 v = *(const floatx4*)(X + (size_t)(row0 + r) * 256 + c0 + c4);
            bf16x4 vh, vl;
#pragma unroll
            for (int ii = 0; ii < 4; ii++) {
                bf16_t h, l; split_hl(v[ii], h, l);
                vh[ii] = h; vl[ii] = l;
            }
            *(bf16x4*)(&Xh[r * 40 + c4]) = vh;
            *(bf16x4*)(&Xl[r * 40 + c4]) = vl;
        }
#pragma unroll
        for (int i = 0; i < 4; i++) {
            int idx = i * 256 + tid;
            int d = idx >> 2, c8 = (idx & 3) * 8;
            *(bf16x8*)(&Wh[d * 40 + c8]) = *(const bf16x8*)(Wzh + d * 256 + c0 + c8);
            *(bf16x8*)(&Wl[d * 40 + c8]) = *(const bf16x8*)(Wzl + d * 256 + c0 + c8);
        }
        __syncthreads();
        bf16x8 ah = *(const bf16x8*)(&Xh[(w * 16 + m) * 40 + q * 8]);
        bf16x8 al = *(const bf16x8*)(&Xl[(w * 16 + m) * 40 + q * 8]);
#pragma unroll
        for (int nt = 0; nt < 16; nt++) {
            bf16x8 bh = *(const bf16x8*)(&Wh[(nt * 16 + m) * 40 + q * 8]);
            bf16x8 bl = *(const bf16x8*)(&Wl[(nt * 16 + m) * 40 + q * 8]);
            acc[nt] = __builtin_amdgcn_mfma_f32_16x16x32_bf16(ah, bh, acc[nt], 0, 0, 0);
            acc[nt] = __builtin_amdgcn_mfma_f32_16x16x32_bf16(ah, bl, acc[nt], 0, 0, 0);
            acc[nt] = __builtin_amdgcn_mfma_f32_16x16x32_bf16(al, bh, acc[nt], 0, 0, 0);
        }
        __syncthreads();
    }
    const int rbase = row0 + w * 16 + q * 4;
    if (z < 2) {
        f16_t* H = (z == 0) ? H1f : H2f;
#pragma unroll
        for (int nt = 0; nt < 16; nt++)
#pragma unroll
            for (int r = 0; r < 4; r++)
                H[(size_t)(rbase + r) * 256 + nt * 16 + m] = (f16_t)acc[nt][r];
    } else {
#pragma unroll
        for (int nt = 0; nt < 16; nt++)
#pragma unroll
            for (int r = 0; r < 4; r++) {
                int token = rbase + r;
                int b = token >> 11, n = token & 2047;
                H3t[(size_t)(b * 256 + nt * 16 + m) * 2048 + n] = (f16_t)acc[nt][r];
            }
    }
}

// ---------------- kernel 3: flash attention, 32 q/wave, single-fp16 Q and K ----------------
// r10 skeleton minus Klo. Register budget (512-thr block -> 256/wave unified):
// o 128 (AGPR) + qf 64 + sa 16 + staging 16 + temps ~30 = ~254 -> no spill.
__global__ __launch_bounds__(512, 1) void attn_kernel(
    const f16_t* __restrict__ H1f, const f16_t* __restrict__ H2f,
    const f16_t* __restrict__ H3t, const unsigned* __restrict__ adjbits,
    f16_t* __restrict__ Opart, float* __restrict__ mpart, float* __restrict__ lpart,
    int klen) {
    __shared__ __align__(16) char smem[57856];
    f16_t* Kf  = (f16_t*)smem;                 // [32 keys][264]  16,896 B @ 0
    f16_t* Vf  = (f16_t*)(smem + 16896);       // [256 d][40]     20,480 B
    f16_t* Plb = (f16_t*)(smem + 37376);       // 8 x [32 q][40]  20,480 B

    const int b = blockIdx.y;
    const int q0b = blockIdx.x * 256;
    const int kz = blockIdx.z;
    const int tid = threadIdx.x;
    const int w = tid >> 6, lane = tid & 63;
    const int lq = lane & 31;        // q-col / key-row / d-row index
    const int h = lane >> 5;         // k-half selector
    const int qg = q0b + w * 32 + lq;
    f16_t* Pl = Plb + w * 1280;      // this wave's 32x40 P buffer

    // ---- Q fragments in registers: B[k][n=q], single fp16, 16 chunks of k=16 ----
    f16x8 qf[16];
    {
        const f16_t* qr = H1f + (size_t)(b * 2048 + qg) * 256;
#pragma unroll
        for (int ck = 0; ck < 16; ck++)
            qf[ck] = *(const f16x8*)(qr + ck * 16 + h * 8);
    }

    float m_run = -3.0e38f, l_run = 0.f;
    floatx16 o[8];
#pragma unroll
    for (int t = 0; t < 8; t++) o[t] = (floatx16)(0.f);

    f16x8 rk[2], rv[2];
    const int kbeg = kz * klen, kend = kbeg + klen;

    // prefetch first K/V tile (1024 16B granules each; 512 thr -> 2 each)
#pragma unroll
    for (int i = 0; i < 2; i++) {
        int ci = i * 512 + tid;
        int krow = ci >> 5, kg = ci & 31;
        rk[i] = *(const f16x8*)(H2f + (size_t)(b * 2048 + kbeg + krow) * 256 + kg * 8);
        int vd = ci >> 2, vg = ci & 3;
        rv[i] = *(const f16x8*)(H3t + (size_t)(b * 256 + vd) * 2048 + kbeg + vg * 8);
    }

    for (int k0 = kbeg; k0 < kend; k0 += 32) {
        __syncthreads();   // prior iter's LDS readers done
#pragma unroll
        for (int i = 0; i < 2; i++) {
            int ci = i * 512 + tid;
            int krow = ci >> 5, kg = ci & 31;
            *(f16x8*)(&Kf[krow * 264 + kg * 8]) = rk[i];
            int vd = ci >> 2, vg = ci & 3;
            *(f16x8*)(&Vf[vd * 40 + vg * 8]) = rv[i];
        }
        __syncthreads();
        if (k0 + 32 < kend) {   // prefetch next tile while computing
            int kn = k0 + 32;
#pragma unroll
            for (int i = 0; i < 2; i++) {
                int ci = i * 512 + tid;
                int krow = ci >> 5, kg = ci & 31;
                rk[i] = *(const f16x8*)(H2f + (size_t)(b * 2048 + kn + krow) * 256 + kg * 8);
                int vd = ci >> 2, vg = ci & 3;
                rv[i] = *(const f16x8*)(H3t + (size_t)(b * 256 + vd) * 2048 + kn + vg * 8);
            }
        }

        // ---- S^T = K·Q^T : one chain, 16 MFMAs ----
        floatx16 sa = (floatx16)(0.f);
#pragma unroll
        for (int ck = 0; ck < 16; ck++) {
            f16x8 kh = *(const f16x8*)(&Kf[lq * 264 + ck * 16 + h * 8]);
            sa = __builtin_amdgcn_mfma_f32_32x32x16_f16(kh, qf[ck], sa, 0, 0, 0);
        }

        // ---- leaky-relu + mask + per-q (per-lane) tile max, in place ----
        unsigned aw = adjbits[(size_t)qg * 64 + (k0 >> 5)];
        unsigned awh = h ? (aw >> 4) : aw;   // fold key's +4h bit into the shift
        float tmax = -3.0e38f;
#pragma unroll
        for (int r = 0; r < 16; r++) {
            float v = sa[r];
            v = (v > 0.f) ? v : 0.2f * v;
            int keyl = (r & 3) + 8 * (r >> 2);   // + 4h via awh
            v = ((awh >> keyl) & 1u) ? v : -1.0e12f;
            sa[r] = v;
            tmax = fmaxf(tmax, v);
        }
        tmax = fmaxf(tmax, __shfl_xor(tmax, 32, 64));

        // ---- online softmax (skip rescale when max didn't rise) ----
        float mnew = fmaxf(m_run, tmax);
        if (__any(mnew > m_run)) {
            float alpha = __expf(m_run - mnew);
            m_run = mnew;
            l_run *= alpha;
#pragma unroll
            for (int t = 0; t < 8; t++)
#pragma unroll
                for (int r = 0; r < 16; r++) o[t][r] *= alpha;
        }
        float rs = 0.f;
#pragma unroll
        for (int r = 0; r < 16; r++) {
            float e = __expf(sa[r] - m_run);
            sa[r] = e;
            rs += e;
        }
        rs += __shfl_xor(rs, 32, 64);
        l_run += rs;

        // ---- P: C-layout -> per-wave LDS [q][key] -> B-layout frags ----
#pragma unroll
        for (int mreg = 0; mreg < 8; mreg++) {
            int keyl = 2 * (mreg & 1) + 8 * (mreg >> 1) + 4 * h;
            f16x2 pk;
            pk[0] = (f16_t)sa[2 * mreg];
            pk[1] = (f16_t)sa[2 * mreg + 1];
            *(f16x2*)(&Pl[lq * 40 + keyl]) = pk;
        }
        f16x8 pf0 = *(const f16x8*)(&Pl[lq * 40 + h * 8]);
        f16x8 pf1 = *(const f16x8*)(&Pl[lq * 40 + 16 + h * 8]);

        // ---- O^T += V^T·P : A = V-frag (m=d), B = P-frag (n=q) ----
#pragma unroll
        for (int t = 0; t < 8; t++) {
            f16x8 v0 = *(const f16x8*)(&Vf[(t * 32 + lq) * 40 + h * 8]);
            f16x8 v1 = *(const f16x8*)(&Vf[(t * 32 + lq) * 40 + 16 + h * 8]);
            o[t] = __builtin_amdgcn_mfma_f32_32x32x16_f16(v0, pf0, o[t], 0, 0, 0);
            o[t] = __builtin_amdgcn_mfma_f32_32x32x16_f16(v1, pf1, o[t], 0, 0, 0);
        }
    }

    // ---- epilogue: per-wave LDS transpose O^T -> row-major fp16 partials ----
    const int rowg = kz * 16384 + b * 2048 + q0b + w * 32;
    float* LT = ((float*)smem) + w * 1152;   // 8 waves x 4608 B = 36,864 <= 57,856
#pragma unroll 1
    for (int t = 0; t < 8; t++) {
        __syncthreads();
#pragma unroll
        for (int r = 0; r < 16; r++) {
            int dsub = (r & 3) + 8 * (r >> 2) + 4 * h;
            LT[lq * 36 + dsub] = o[t][r];
        }
        __syncthreads();
#pragma unroll
        for (int pp = 0; pp < 4; pp++) {
            int qq = pp * 8 + (lane >> 3), dc = (lane & 7) * 4;
            floatx4 v = *(const floatx4*)(&LT[qq * 36 + dc]);
            f16x4 vh;
#pragma unroll
            for (int ii = 0; ii < 4; ii++) vh[ii] = (f16_t)v[ii];
            *(f16x4*)(&Opart[(size_t)(rowg + qq) * 256 + t * 32 + dc]) = vh;
        }
    }
    if (h == 0) {
        mpart[rowg + lq] = m_run;
        lpart[rowg + lq] = l_run;
    }
}

// ---------------- kernel 4: merge splits + normalize + relu ----------------
__global__ __launch_bounds__(256) void merge_kernel(
    const f16_t* __restrict__ Opart, const float* __restrict__ mpart,
    const float* __restrict__ lpart, float* __restrict__ out, int S) {
    int gid = blockIdx.x * 256 + threadIdx.x;   // 16384 rows x 64 col-chunks
    int row = gid >> 6, c4 = (gid & 63) * 4;
    float M = -3.0e38f;
    for (int s = 0; s < S; s++) M = fmaxf(M, mpart[s * 16384 + row]);
    float denom = 0.f;
    float4 acc = make_float4(0.f, 0.f, 0.f, 0.f);
    for (int s = 0; s < S; s++) {
        float sc = __expf(mpart[s * 16384 + row] - M);
        denom += lpart[s * 16384 + row] * sc;
        f16x4 v = *(const f16x4*)(Opart + ((size_t)(s * 16384 + row)) * 256 + c4);
        acc.x += (float)v[0] * sc; acc.y += (float)v[1] * sc;
        acc.z += (float)v[2] * sc; acc.w += (float)v[3] * sc;
    }
    float inv = 1.f / denom;
    float4 r;
    r.x = fmaxf(acc.x * inv, 0.f);
    r.y = fmaxf(acc.y * inv, 0.f);
    r.z = fmaxf(acc.z * inv, 0.f);
    r.w = fmaxf(acc.w * inv, 0.f);
    *(float4*)(out + (size_t)row * 256 + c4) = r;
}

extern "C" void kernel_launch(void* const* d_in, const int* in_sizes, int n_in,
                              void* d_out, int out_size, void* d_ws, size_t ws_size,
                              hipStream_t stream) {
    const float* X   = (const float*)d_in[0];
    const int*   adj = (const int*)d_in[1];
    const float* W1  = (const float*)d_in[2];
    const float* W2  = (const float*)d_in[3];
    const float* W3  = (const float*)d_in[4];
    float* out = (float*)d_out;

    char* ws = (char*)d_ws;
    f16_t* H1f = (f16_t*)(ws + (size_t)0 * S_H * 2);
    f16_t* H2f = (f16_t*)(ws + (size_t)1 * S_H * 2);
    f16_t* H3t = (f16_t*)(ws + (size_t)2 * S_H * 2);
    size_t off = (size_t)3 * S_H * 2;                    // 25,165,824
    bf16_t* Wthi = (bf16_t*)(ws + off);                  // 393,216 B
    bf16_t* Wtlo = (bf16_t*)(ws + off + 393216);         // 393,216 B
    float* mpart = (float*)(ws + off);                   // overlays Wt (dead after proj)
    float* lpart = (float*)(ws + off + 262144);          // 4*16384*4 each, fits 786,432
    unsigned* adjb = (unsigned*)(ws + off + 786432);     // 524,288 B
    size_t opart_off = off + 786432 + 524288;            // 26,476,544
    f16_t* Opart = (f16_t*)(ws + opart_off);

    const size_t need4 = opart_off + (size_t)4 * 16384 * 256 * 2;  // 60,030,976
    const size_t need2 = opart_off + (size_t)2 * 16384 * 256 * 2;
    int S = (ws_size >= need4) ? 4 : ((ws_size >= need2) ? 2 : 1);

    adjbits_kernel<<<512, 256, 0, stream>>>(adj, adjb);
    wtrans_kernel<<<dim3(4, 4, 3), 256, 0, stream>>>(W1, W2, W3, Wthi, Wtlo);
    proj_kernel<<<dim3(256, 3), 256, 0, stream>>>(X, Wthi, Wtlo, H1f, H2f, H3t);
    attn_kernel<<<dim3(8, 8, S), 512, 0, stream>>>(H1f, H2f, H3t,
                                                   adjb, Opart, mpart, lpart, 2048 / S);
    merge_kernel<<<4096, 256, 0, stream>>>(Opart, mpart, lpart, out, S);
}